// Round 7
// baseline (2471.683 us; speedup 1.0000x reference)
//
#include <hip/hip_runtime.h>
#include <hip/hip_bf16.h>

typedef __bf16 bf16x8 __attribute__((ext_vector_type(8)));
typedef float f32x4 __attribute__((ext_vector_type(4)));
typedef unsigned long long u64;

#define TSTEPS 256
#define NB 64
#define ID 1024
#define HD 1024
#define KD 2048

// ws layout (bytes)
#define WOFF 0ull
#define VOFF 16777216ull
#define BOFF 18874368ull
#define HMOFF 18890752ull            // 257 h buffers x 65536 elems (bf16), [t][c8][row][8] layout
#define BAROFF 52576256ull           // 256 packed flag dwords (1KB)
#define XBOFF 52580352ull            // xb bf16 [t][row][k] = 33.5MB

__device__ __forceinline__ unsigned short f2b(float f) {
    unsigned int u = __float_as_uint(f);
    unsigned int r = (u + 0x7fffu + ((u >> 16) & 1u)) >> 16;
    return (unsigned short)r;
}

__device__ __forceinline__ bf16x8 as_frag(uint4 u) {
    union { uint4 u; bf16x8 v; } c; c.u = u; return c.v;
}

// order-pinned cached 16B load (issue only; no wait)
__device__ __forceinline__ uint4 ld_b128(const void* p) {
    uint4 r;
    asm volatile("global_load_dwordx4 %0, %1, off" : "=v"(r) : "v"(p));
    return r;
}

__global__ void cvt_x(const float* __restrict__ in, unsigned short* __restrict__ out) {
    size_t i = ((size_t)blockIdx.x * 256 + threadIdx.x) * 8;
    int t = (int)(i >> 16);
    int b = (int)(i >> 10) & 63;
    int k = (int)i & 1023;
    const float* src = in + ((size_t)b << 18) + ((size_t)t << 10) + k;  // x[b][t][k]
    float4 a = *(const float4*)src;
    float4 bb = *(const float4*)(src + 4);
    union { unsigned short h[8]; uint4 u; } o;
    o.h[0] = f2b(a.x); o.h[1] = f2b(a.y); o.h[2] = f2b(a.z); o.h[3] = f2b(a.w);
    o.h[4] = f2b(bb.x); o.h[5] = f2b(bb.y); o.h[6] = f2b(bb.z); o.h[7] = f2b(bb.w);
    *(uint4*)(out + i) = o.u;   // xb[t][b][k]
}

__global__ void cvt_w(const float* __restrict__ Wf, const float* __restrict__ Wi,
                      const float* __restrict__ Wo, const float* __restrict__ Wc,
                      const float* __restrict__ bf_, const float* __restrict__ bi_,
                      const float* __restrict__ bo_, const float* __restrict__ bc_,
                      unsigned short* __restrict__ Wr, float* __restrict__ bias_r) {
    int idx = blockIdx.x * 256 + threadIdx.x;   // 4096*256 total
    int np = idx >> 8;            // n' = hcol*4 + gate
    int k  = (idx & 255) * 8;
    int g = np & 3, h = np >> 2;
    const float* W = (g == 0) ? Wf : (g == 1) ? Wi : (g == 2) ? Wo : Wc;
    const float* src = W + (size_t)h * KD + k;
    float4 a = *(const float4*)src;
    float4 b = *(const float4*)(src + 4);
    union { unsigned short h[8]; uint4 u; } o;
    o.h[0] = f2b(a.x); o.h[1] = f2b(a.y); o.h[2] = f2b(a.z); o.h[3] = f2b(a.w);
    o.h[4] = f2b(b.x); o.h[5] = f2b(b.y); o.h[6] = f2b(b.z); o.h[7] = f2b(b.w);
    *(uint4*)(Wr + (size_t)np * KD + k) = o.u;
    if (k == 0) {
        const float* B = (g == 0) ? bf_ : (g == 1) ? bi_ : (g == 2) ? bo_ : bc_;
        bias_r[np] = B[h];
    }
}

__global__ void cvt_v(const float* __restrict__ V, unsigned short* __restrict__ out) {
    size_t i = ((size_t)blockIdx.x * blockDim.x + threadIdx.x) * 8;
    float4 a = *(const float4*)(V + i);
    float4 b = *(const float4*)(V + i + 4);
    union { unsigned short h[8]; uint4 u; } o;
    o.h[0] = f2b(a.x); o.h[1] = f2b(a.y); o.h[2] = f2b(a.z); o.h[3] = f2b(a.w);
    o.h[4] = f2b(b.x); o.h[5] = f2b(b.y); o.h[6] = f2b(b.z); o.h[7] = f2b(b.w);
    *(uint4*)(out + i) = o.u;
}

__global__ void init_h(unsigned short* __restrict__ h0) {
    size_t i = ((size_t)blockIdx.x * blockDim.x + threadIdx.x) * 8;
    uint4 z = {0, 0, 0, 0};
    *(uint4*)(h0 + i) = z;
}

__global__ void init_bar(unsigned int* __restrict__ flags) {
    flags[threadIdx.x] = 0;
}

__device__ __forceinline__ float sigf(float x) {
    return 1.0f / (1.0f + __expf(-x));
}
__device__ __forceinline__ float tanhfast(float x) {
    return 2.0f / (1.0f + __expf(-2.0f * x)) - 1.0f;
}

// poll all 256 packed flags: one dwordx4 per lane (lane covers 4 contiguous blocks)
__device__ __forceinline__ bool flags_ge(const unsigned int* fp, unsigned int t) {
    uint4 f;
    asm volatile("global_load_dwordx4 %0, %1, off sc0 sc1\n\ts_waitcnt vmcnt(0)"
                 : "=v"(f) : "v"(fp) : "memory");
    bool ok = f.x >= t && f.y >= t && f.z >= t && f.w >= t;
    return __all(ok) != 0;
}

__launch_bounds__(512, 2)
__global__ void lstm_core(const unsigned short* __restrict__ xb,
                          const unsigned short* __restrict__ Wr,
                          const float* __restrict__ bias_r,
                          unsigned short* __restrict__ hm,
                          const unsigned short* __restrict__ Vw,
                          const float* __restrict__ Vbias,
                          float* __restrict__ out,
                          unsigned int* __restrict__ flags) {
    __shared__ float gxp[8][64][20];
    __shared__ int cnt;

    const int bid  = blockIdx.x;       // 256 blocks, 16 gate-cols (4 h-cols) each
    const int tid  = threadIdx.x;      // 512 threads, 8 waves
    const int wave = tid >> 6;
    const int lane = tid & 63;
    const int lrow = lane & 15;
    const int kq   = (lane >> 4) << 3; // 0,8,16,24
    const int n0   = bid << 4;
    const int qr   = (lane >> 4) << 2;

    // cell mapping: waves 4-7 (tid 256..511) are the 256 cell threads
    const int ct   = tid - 256;
    const int ob   = (ct >> 2) & 63;
    const int lhc  = ct & 3;
    const int hcol = (bid << 2) + lhc;
    float4 bb = {0, 0, 0, 0};
    if (tid >= 256) bb = *(const float4*)&bias_r[n0 + (lhc << 2)];

    const bool isx = wave < 4;
    // wptr includes (wave<<8): x-waves cover k 0..1023, h-waves k 1024..2047
    const unsigned short* wptr = Wr + (size_t)(n0 + lrow) * KD + (wave << 8) + kq;

    // loop-invariant weight fragments, asm-pinned into registers (32 VGPR)
    uint4 wfrag[8];
    #pragma unroll
    for (int kk8 = 0; kk8 < 8; ++kk8)
        wfrag[kk8] = ld_b128(wptr + kk8 * 32);
    asm volatile("s_waitcnt vmcnt(0)" ::: "memory");

    int koff = 0;
    if (!isx) koff = ((wave - 4) << 8) + kq;   // h k-base (0..1023 within h) for this lane
    const int xko = (wave << 8) + kq;

    if (tid == 0) *(volatile int*)&cnt = 0;
    __syncthreads();

    float c_reg = 0.f;
    float hlast = 0.f;

    for (int t = 0; t < TSTEPS; ++t) {
        f32x4 acc[4];
        #pragma unroll
        for (int m = 0; m < 4; ++m) acc[m] = (f32x4){0, 0, 0, 0};

        if (isx) {
            const unsigned short* xt = xb + ((size_t)t << 16);
            // issue all 32 loads (order-pinned), wait once, then register-only MFMA
            uint4 xv[4][8];
            #pragma unroll
            for (int kk8 = 0; kk8 < 8; ++kk8)
                #pragma unroll
                for (int m = 0; m < 4; ++m)
                    xv[m][kk8] = ld_b128(xt + (size_t)(m * 16 + lrow) * 1024 + xko + kk8 * 32);
            asm volatile("s_waitcnt vmcnt(0)" ::: "memory");
            __builtin_amdgcn_sched_barrier(0);
            #pragma unroll
            for (int kk8 = 0; kk8 < 8; ++kk8)
                #pragma unroll
                for (int m = 0; m < 4; ++m)
                    acc[m] = __builtin_amdgcn_mfma_f32_16x16x32_bf16(as_frag(xv[m][kk8]),
                                                                     as_frag(wfrag[kk8]), acc[m], 0, 0, 0);
        } else {
            // all 4 h-waves poll the packed flags directly
            const unsigned int* fp = flags + (lane << 2);
            int iters = 0;
            while (!flags_ge(fp, (unsigned int)t)) {
                if (++iters > (1 << 22)) break;
                __builtin_amdgcn_s_sleep(1);
            }
            __builtin_amdgcn_sched_barrier(0);
            // h_t in [c8][row][8] layout: one b128 per fragment; issue all 32, wait once
            const unsigned short* hmt = hm + ((size_t)t << 16);
            uint4 hv[4][8];
            #pragma unroll
            for (int kk8 = 0; kk8 < 8; ++kk8) {
                int c8 = (koff >> 3) + kk8 * 4;
                #pragma unroll
                for (int m = 0; m < 4; ++m)
                    hv[m][kk8] = ld_b128(hmt + (size_t)c8 * 512 + (m * 16 + lrow) * 8);
            }
            asm volatile("s_waitcnt vmcnt(0)" ::: "memory");
            __builtin_amdgcn_sched_barrier(0);
            #pragma unroll
            for (int kk8 = 0; kk8 < 8; ++kk8)
                #pragma unroll
                for (int m = 0; m < 4; ++m)
                    acc[m] = __builtin_amdgcn_mfma_f32_16x16x32_bf16(as_frag(hv[m][kk8]),
                                                                     as_frag(wfrag[kk8]), acc[m], 0, 0, 0);
        }

        #pragma unroll
        for (int m = 0; m < 4; ++m)
            #pragma unroll
            for (int r = 0; r < 4; ++r)
                gxp[wave][m * 16 + qr + r][lrow] = acc[m][r];
        __syncthreads();   // S1: gate partials ready

        if (tid >= 256) {
            float fpre = bb.x, ipre = bb.y, opre = bb.z, gpre = bb.w;
            #pragma unroll
            for (int w = 0; w < 8; ++w) {
                float4 s = *(const float4*)&gxp[w][ob][lhc << 2];
                fpre += s.x; ipre += s.y; opre += s.z; gpre += s.w;
            }
            float fg = sigf(fpre);
            float ig = sigf(ipre);
            float og = sigf(opre);
            float gg = tanhfast(gpre);
            c_reg = fg * c_reg + ig * gg;
            float hh = og * tanhfast(c_reg);
            if (t == TSTEPS - 1) hlast = hh;

            // publish: shfl-pack 4 bf16 -> one 8B store per 4 lanes ([c8][row][8] layout)
            unsigned int hb = f2b(hh);
            unsigned int p1 = __shfl_down(hb, 1);
            unsigned int p2 = __shfl_down(hb, 2);
            unsigned int p3 = __shfl_down(hb, 3);
            if ((lane & 3) == 0) {
                u64 v = (u64)hb | ((u64)p1 << 16) | ((u64)p2 << 32) | ((u64)p3 << 48);
                unsigned short* dst = hm + ((size_t)(t + 1) << 16)
                                       + (size_t)(bid >> 1) * 512 + (size_t)ob * 8 + ((bid & 1) << 2);
                asm volatile("global_store_dwordx2 %0, %1, off sc0 sc1" :: "v"(dst), "v"(v) : "memory");
            }
            asm volatile("s_waitcnt vmcnt(0)" ::: "memory");
            if (wave != 7) {
                if (lane == 0) atomicAdd(&cnt, 1);
            } else if (lane == 0) {
                int spin = 0;
                while (*(volatile int*)&cnt < 3 * (t + 1)) {
                    if (++spin > (1 << 24)) break;
                }
                unsigned int* fdst = flags + bid;
                unsigned int fv = (unsigned int)(t + 1);
                asm volatile("global_store_dword %0, %1, off sc0 sc1" :: "v"(fdst), "v"(fv) : "memory");
            }
        }
        __syncthreads();   // S2: gxp consumed, safe to overwrite next step
    }

    if (tid >= 256) {
        out[(size_t)ob * HD + hcol] = c_reg;                    // c
        out[65536 + (size_t)ob * HD + hcol] = hlast;            // h
    }

    // final projection: last_out = h_256 @ V^T + V_b, blocks 0..63 (N=1024)
    if (bid < 64) {
        {
            const unsigned int* fp = flags + (lane << 2);
            int iters = 0;
            while (!flags_ge(fp, 256u)) {
                if (++iters > (1 << 22)) break;
                __builtin_amdgcn_s_sleep(1);
            }
        }
        __builtin_amdgcn_sched_barrier(0);
        f32x4 acc[4];
        #pragma unroll
        for (int m = 0; m < 4; ++m) acc[m] = (f32x4){0, 0, 0, 0};
        const int ko2 = (wave << 7) + kq;                       // K=1024 split 8 x 128
        const unsigned short* vp = Vw + (size_t)(n0 + lrow) * HD + ko2;
        const unsigned short* hmt = hm + ((size_t)TSTEPS << 16);
        uint4 pv[4][4], pw[4];
        #pragma unroll
        for (int kk8 = 0; kk8 < 4; ++kk8) {
            pw[kk8] = ld_b128(vp + kk8 * 32);
            int c8 = (ko2 >> 3) + kk8 * 4;
            #pragma unroll
            for (int m = 0; m < 4; ++m)
                pv[m][kk8] = ld_b128(hmt + (size_t)c8 * 512 + (m * 16 + lrow) * 8);
        }
        asm volatile("s_waitcnt vmcnt(0)" ::: "memory");
        __builtin_amdgcn_sched_barrier(0);
        #pragma unroll
        for (int kk8 = 0; kk8 < 4; ++kk8)
            #pragma unroll
            for (int m = 0; m < 4; ++m)
                acc[m] = __builtin_amdgcn_mfma_f32_16x16x32_bf16(as_frag(pv[m][kk8]),
                                                                 as_frag(pw[kk8]), acc[m], 0, 0, 0);
        #pragma unroll
        for (int m = 0; m < 4; ++m)
            #pragma unroll
            for (int r = 0; r < 4; ++r)
                gxp[wave][m * 16 + qr + r][lrow] = acc[m][r];
        __syncthreads();
        if (tid >= 256) {
            float4 vb = *(const float4*)&Vbias[n0 + (lhc << 2)];
            float4 res = vb;
            #pragma unroll
            for (int w = 0; w < 8; ++w) {
                float4 s = *(const float4*)&gxp[w][ob][lhc << 2];
                res.x += s.x; res.y += s.y; res.z += s.z; res.w += s.w;
            }
            *(float4*)&out[131072 + (size_t)ob * 1024 + n0 + (lhc << 2)] = res;
        }
    }
}

extern "C" void kernel_launch(void* const* d_in, const int* in_sizes, int n_in,
                              void* d_out, int out_size, void* d_ws, size_t ws_size,
                              hipStream_t stream) {
    const float* x   = (const float*)d_in[0];
    const float* Wf  = (const float*)d_in[1];
    const float* bf_ = (const float*)d_in[2];
    const float* Wi  = (const float*)d_in[3];
    const float* bi_ = (const float*)d_in[4];
    const float* Wc  = (const float*)d_in[5];
    const float* bc_ = (const float*)d_in[6];
    const float* Wo  = (const float*)d_in[7];
    const float* bo_ = (const float*)d_in[8];
    const float* Vw  = (const float*)d_in[9];
    const float* Vb  = (const float*)d_in[10];

    char* ws = (char*)d_ws;
    unsigned short* Wr     = (unsigned short*)(ws + WOFF);
    unsigned short* Vbf    = (unsigned short*)(ws + VOFF);
    float*          bias_r = (float*)(ws + BOFF);
    unsigned short* hm     = (unsigned short*)(ws + HMOFF);
    unsigned int*   flags  = (unsigned int*)(ws + BAROFF);
    unsigned short* xbb    = (unsigned short*)(ws + XBOFF);
    float*          outp   = (float*)d_out;

    cvt_x <<<8192, 256, 0, stream>>>(x, xbb);
    cvt_w <<<4096, 256, 0, stream>>>(Wf, Wi, Wo, Wc, bf_, bi_, bo_, bc_, Wr, bias_r);
    cvt_v <<<512, 256, 0, stream>>>(Vw, Vbf);
    init_h<<<32, 256, 0, stream>>>(hm);
    init_bar<<<1, 256, 0, stream>>>(flags);

    void* args[] = {&xbb, &Wr, &bias_r, &hm, &Vbf, (void*)&Vb, &outp, &flags};
    hipLaunchCooperativeKernel((const void*)lstm_core, dim3(256), dim3(512), args, 0, stream);
}

// Round 9
// 1462.060 us; speedup vs baseline: 1.6905x; 1.6905x over previous
//
#include <hip/hip_runtime.h>
#include <hip/hip_bf16.h>

typedef __bf16 bf16x8 __attribute__((ext_vector_type(8)));
typedef float f32x4 __attribute__((ext_vector_type(4)));
typedef unsigned long long u64;

#define TSTEPS 256
#define NB 64
#define ID 1024
#define HD 1024
#define KD 2048

// ws layout (bytes)
#define WOFF 0ull
#define VOFF 16777216ull
#define BOFF 18874368ull
#define HMOFF 18890752ull            // 257 h buffers x 65536 bf16, [t][c8][row][8] layout
#define XBOFF 52580352ull            // xb bf16 [t][row][k] = 33.5MB

#define SENT 0xFFFFFFFFu

__device__ __forceinline__ unsigned short f2b(float f) {
    unsigned int u = __float_as_uint(f);
    unsigned int r = (u + 0x7fffu + ((u >> 16) & 1u)) >> 16;
    return (unsigned short)r;
}

__device__ __forceinline__ bf16x8 as_frag(uint4 u) {
    union { uint4 u; bf16x8 v; } c; c.u = u; return c.v;
}

// coherence-point (L2-bypass) 16B load, issue only
__device__ __forceinline__ uint4 ld_b128_cp(const void* p) {
    uint4 r;
    asm volatile("global_load_dwordx4 %0, %1, off sc0 sc1" : "=v"(r) : "v"(p));
    return r;
}
// order-pinned cached 16B load (for loop-invariant W pinning)
__device__ __forceinline__ uint4 ld_b128(const void* p) {
    uint4 r;
    asm volatile("global_load_dwordx4 %0, %1, off" : "=v"(r) : "v"(p));
    return r;
}

__global__ void cvt_x(const float* __restrict__ in, unsigned short* __restrict__ out) {
    size_t i = ((size_t)blockIdx.x * 256 + threadIdx.x) * 8;
    int t = (int)(i >> 16);
    int b = (int)(i >> 10) & 63;
    int k = (int)i & 1023;
    const float* src = in + ((size_t)b << 18) + ((size_t)t << 10) + k;  // x[b][t][k]
    float4 a = *(const float4*)src;
    float4 bb = *(const float4*)(src + 4);
    union { unsigned short h[8]; uint4 u; } o;
    o.h[0] = f2b(a.x); o.h[1] = f2b(a.y); o.h[2] = f2b(a.z); o.h[3] = f2b(a.w);
    o.h[4] = f2b(bb.x); o.h[5] = f2b(bb.y); o.h[6] = f2b(bb.z); o.h[7] = f2b(bb.w);
    *(uint4*)(out + i) = o.u;   // xb[t][b][k]
}

__global__ void cvt_w(const float* __restrict__ Wf, const float* __restrict__ Wi,
                      const float* __restrict__ Wo, const float* __restrict__ Wc,
                      const float* __restrict__ bf_, const float* __restrict__ bi_,
                      const float* __restrict__ bo_, const float* __restrict__ bc_,
                      unsigned short* __restrict__ Wr, float* __restrict__ bias_r) {
    int idx = blockIdx.x * 256 + threadIdx.x;   // 4096*256 total
    int np = idx >> 8;            // n' = hcol*4 + gate
    int k  = (idx & 255) * 8;
    int g = np & 3, h = np >> 2;
    const float* W = (g == 0) ? Wf : (g == 1) ? Wi : (g == 2) ? Wo : Wc;
    const float* src = W + (size_t)h * KD + k;
    float4 a = *(const float4*)src;
    float4 b = *(const float4*)(src + 4);
    union { unsigned short h[8]; uint4 u; } o;
    o.h[0] = f2b(a.x); o.h[1] = f2b(a.y); o.h[2] = f2b(a.z); o.h[3] = f2b(a.w);
    o.h[4] = f2b(b.x); o.h[5] = f2b(b.y); o.h[6] = f2b(b.z); o.h[7] = f2b(b.w);
    *(uint4*)(Wr + (size_t)np * KD + k) = o.u;
    if (k == 0) {
        const float* B = (g == 0) ? bf_ : (g == 1) ? bi_ : (g == 2) ? bo_ : bc_;
        bias_r[np] = B[h];
    }
}

__global__ void cvt_v(const float* __restrict__ V, unsigned short* __restrict__ out) {
    size_t i = ((size_t)blockIdx.x * blockDim.x + threadIdx.x) * 8;
    float4 a = *(const float4*)(V + i);
    float4 b = *(const float4*)(V + i + 4);
    union { unsigned short h[8]; uint4 u; } o;
    o.h[0] = f2b(a.x); o.h[1] = f2b(a.y); o.h[2] = f2b(a.z); o.h[3] = f2b(a.w);
    o.h[4] = f2b(b.x); o.h[5] = f2b(b.y); o.h[6] = f2b(b.z); o.h[7] = f2b(b.w);
    *(uint4*)(out + i) = o.u;
}

__global__ void init_h(unsigned short* __restrict__ h0) {     // buffer 0 = zeros
    size_t i = ((size_t)blockIdx.x * blockDim.x + threadIdx.x) * 8;
    uint4 z = {0, 0, 0, 0};
    *(uint4*)(h0 + i) = z;
}

__global__ void init_sent(unsigned short* __restrict__ h1) {  // buffers 1..256 = sentinel
    size_t i = ((size_t)blockIdx.x * blockDim.x + threadIdx.x) * 8;
    uint4 s = {SENT, SENT, SENT, SENT};
    *(uint4*)(h1 + i) = s;
}

__device__ __forceinline__ float sigf(float x) {
    return 1.0f / (1.0f + __expf(-x));
}
__device__ __forceinline__ float tanhfast(float x) {
    return 2.0f / (1.0f + __expf(-2.0f * x)) - 1.0f;
}

__launch_bounds__(512, 1)
__global__ void lstm_core(const unsigned short* __restrict__ xb,
                          const unsigned short* __restrict__ Wr,
                          const float* __restrict__ bias_r,
                          unsigned short* __restrict__ hm,
                          const unsigned short* __restrict__ Vw,
                          const float* __restrict__ Vbias,
                          float* __restrict__ out) {
    __shared__ float gxp[8][64][20];

    const int bid  = blockIdx.x;       // 256 blocks, 16 gate-cols (4 h-cols) each
    const int tid  = threadIdx.x;      // 512 threads, 8 waves
    const int wave = tid >> 6;
    const int lane = tid & 63;
    const int lrow = lane & 15;
    const int kq   = (lane >> 4) << 3; // 0,8,16,24
    const int n0   = bid << 4;
    const int qr   = (lane >> 4) << 2;

    // cell mapping: waves 4-7 (tid 256..511) are the 256 cell threads
    const int ct   = tid - 256;
    const int ob   = (ct >> 2) & 63;
    const int lhc  = ct & 3;
    const int hcol = (bid << 2) + lhc;
    float4 bb = {0, 0, 0, 0};
    if (tid >= 256) bb = *(const float4*)&bias_r[n0 + (lhc << 2)];

    const bool isx = wave < 4;
    // wptr includes (wave<<8): x-waves cover k 0..1023, h-waves k 1024..2047
    const unsigned short* wptr = Wr + (size_t)(n0 + lrow) * KD + (wave << 8) + kq;

    // loop-invariant weight fragments, asm-pinned into registers (32 VGPR)
    uint4 wfrag[8];
    #pragma unroll
    for (int kk8 = 0; kk8 < 8; ++kk8)
        wfrag[kk8] = ld_b128(wptr + kk8 * 32);
    asm volatile("s_waitcnt vmcnt(0)" ::: "memory");
    __builtin_amdgcn_sched_barrier(0);

    int koff = 0;
    if (!isx) koff = ((wave - 4) << 8) + kq;   // h k-base (0..1023) for this lane
    const int xko = (wave << 8) + kq;

    float c_reg = 0.f;
    float hlast = 0.f;

    for (int t = 0; t < TSTEPS; ++t) {
        f32x4 acc[4];
        #pragma unroll
        for (int m = 0; m < 4; ++m) acc[m] = (f32x4){0, 0, 0, 0};

        if (isx) {
            // x-part: off the critical path; plain cached loads, compiler-scheduled
            const unsigned short* xt = xb + ((size_t)t << 16);
            #pragma unroll
            for (int kk8 = 0; kk8 < 8; ++kk8)
                #pragma unroll
                for (int m = 0; m < 4; ++m)
                    acc[m] = __builtin_amdgcn_mfma_f32_16x16x32_bf16(
                        *(const bf16x8*)(xt + (size_t)(m * 16 + lrow) * 1024 + xko + kk8 * 32),
                        as_frag(wfrag[kk8]), acc[m], 0, 0, 0);
        } else {
            // h-part: in-band sentinel polling — the data IS the flag.
            const unsigned short* hmt = hm + ((size_t)t << 16);
            const int c8b = koff >> 3;
            uint4 hA[4][4], hB[4][4];

            // half A (kk8 0..3): poll until every dword != SENT
            int itA = 0;
            for (;;) {
                #pragma unroll
                for (int j = 0; j < 4; ++j)
                    #pragma unroll
                    for (int m = 0; m < 4; ++m)
                        hA[j][m] = ld_b128_cp(hmt + (size_t)(c8b + j * 4) * 512 + (m * 16 + lrow) * 8);
                asm volatile("s_waitcnt vmcnt(0)" ::: "memory");
                __builtin_amdgcn_sched_barrier(0);   // rule #18: pin compares after the wait
                unsigned int bad = 0;
                #pragma unroll
                for (int j = 0; j < 4; ++j)
                    #pragma unroll
                    for (int m = 0; m < 4; ++m)
                        bad |= (hA[j][m].x == SENT) | (hA[j][m].y == SENT) |
                               (hA[j][m].z == SENT) | (hA[j][m].w == SENT);
                if (__all(bad == 0) || ++itA > (1 << 14)) break;
            }
            __builtin_amdgcn_sched_barrier(0);

            // issue half B early; its RT hides under half-A MFMAs
            #pragma unroll
            for (int j = 0; j < 4; ++j)
                #pragma unroll
                for (int m = 0; m < 4; ++m)
                    hB[j][m] = ld_b128_cp(hmt + (size_t)(c8b + (j + 4) * 4) * 512 + (m * 16 + lrow) * 8);
            __builtin_amdgcn_sched_barrier(0);

            #pragma unroll
            for (int j = 0; j < 4; ++j)
                #pragma unroll
                for (int m = 0; m < 4; ++m)
                    acc[m] = __builtin_amdgcn_mfma_f32_16x16x32_bf16(as_frag(hA[j][m]),
                                                                     as_frag(wfrag[j]), acc[m], 0, 0, 0);

            int itB = 0;
            for (;;) {
                asm volatile("s_waitcnt vmcnt(0)" ::: "memory");
                __builtin_amdgcn_sched_barrier(0);   // rule #18
                unsigned int bad = 0;
                #pragma unroll
                for (int j = 0; j < 4; ++j)
                    #pragma unroll
                    for (int m = 0; m < 4; ++m)
                        bad |= (hB[j][m].x == SENT) | (hB[j][m].y == SENT) |
                               (hB[j][m].z == SENT) | (hB[j][m].w == SENT);
                if (__all(bad == 0) || ++itB > (1 << 14)) break;
                #pragma unroll
                for (int j = 0; j < 4; ++j)
                    #pragma unroll
                    for (int m = 0; m < 4; ++m)
                        hB[j][m] = ld_b128_cp(hmt + (size_t)(c8b + (j + 4) * 4) * 512 + (m * 16 + lrow) * 8);
            }
            __builtin_amdgcn_sched_barrier(0);

            #pragma unroll
            for (int j = 0; j < 4; ++j)
                #pragma unroll
                for (int m = 0; m < 4; ++m)
                    acc[m] = __builtin_amdgcn_mfma_f32_16x16x32_bf16(as_frag(hB[j][m]),
                                                                     as_frag(wfrag[j + 4]), acc[m], 0, 0, 0);
        }

        #pragma unroll
        for (int m = 0; m < 4; ++m)
            #pragma unroll
            for (int r = 0; r < 4; ++r)
                gxp[wave][m * 16 + qr + r][lrow] = acc[m][r];
        __syncthreads();   // S1: gate partials ready

        if (tid >= 256) {
            float fpre = bb.x, ipre = bb.y, opre = bb.z, gpre = bb.w;
            #pragma unroll
            for (int w = 0; w < 8; ++w) {
                float4 s = *(const float4*)&gxp[w][ob][lhc << 2];
                fpre += s.x; ipre += s.y; opre += s.z; gpre += s.w;
            }
            float fg = sigf(fpre);
            float ig = sigf(ipre);
            float og = sigf(opre);
            float gg = tanhfast(gpre);
            c_reg = fg * c_reg + ig * gg;
            float hh = og * tanhfast(c_reg);
            if (t == TSTEPS - 1) hlast = hh;

            // fire-and-forget publish: one 8B sc0sc1 store per 4 lanes, no ack
            unsigned int hb = f2b(hh);
            unsigned int p1 = __shfl_down(hb, 1);
            unsigned int p2 = __shfl_down(hb, 2);
            unsigned int p3 = __shfl_down(hb, 3);
            if ((lane & 3) == 0) {
                u64 v = (u64)hb | ((u64)p1 << 16) | ((u64)p2 << 32) | ((u64)p3 << 48);
                unsigned short* dst = hm + ((size_t)(t + 1) << 16)
                                       + (size_t)(bid >> 1) * 512 + (size_t)ob * 8 + ((bid & 1) << 2);
                asm volatile("global_store_dwordx2 %0, %1, off sc0 sc1" :: "v"(dst), "v"(v) : "memory");
            }
        }
        __syncthreads();   // S2: gxp consumed, safe to overwrite next step
    }

    if (tid >= 256) {
        out[(size_t)ob * HD + hcol] = c_reg;                    // c
        out[65536 + (size_t)ob * HD + hcol] = hlast;            // h
    }

    // final projection: last_out = h_256 @ V^T + V_b, blocks 0..63 (N=1024)
    if (bid < 64) {
        f32x4 acc[4];
        #pragma unroll
        for (int m = 0; m < 4; ++m) acc[m] = (f32x4){0, 0, 0, 0};
        const int ko2 = (wave << 7) + kq;                       // K=1024 split 8 x 128
        const unsigned short* vp = Vw + (size_t)(n0 + lrow) * HD + ko2;
        const unsigned short* hmt = hm + ((size_t)TSTEPS << 16);
        const int c8b = ko2 >> 3;
        uint4 pw[4], pv[4][4];
        #pragma unroll
        for (int j = 0; j < 4; ++j)
            pw[j] = ld_b128(vp + j * 32);
        int it = 0;
        for (;;) {
            #pragma unroll
            for (int j = 0; j < 4; ++j)
                #pragma unroll
                for (int m = 0; m < 4; ++m)
                    pv[j][m] = ld_b128_cp(hmt + (size_t)(c8b + j * 4) * 512 + (m * 16 + lrow) * 8);
            asm volatile("s_waitcnt vmcnt(0)" ::: "memory");
            __builtin_amdgcn_sched_barrier(0);   // rule #18
            unsigned int bad = 0;
            #pragma unroll
            for (int j = 0; j < 4; ++j)
                #pragma unroll
                for (int m = 0; m < 4; ++m)
                    bad |= (pv[j][m].x == SENT) | (pv[j][m].y == SENT) |
                           (pv[j][m].z == SENT) | (pv[j][m].w == SENT);
            if (__all(bad == 0) || ++it > (1 << 14)) break;
        }
        __builtin_amdgcn_sched_barrier(0);
        #pragma unroll
        for (int j = 0; j < 4; ++j)
            #pragma unroll
            for (int m = 0; m < 4; ++m)
                acc[m] = __builtin_amdgcn_mfma_f32_16x16x32_bf16(as_frag(pv[j][m]),
                                                                 as_frag(pw[j]), acc[m], 0, 0, 0);
        #pragma unroll
        for (int m = 0; m < 4; ++m)
            #pragma unroll
            for (int r = 0; r < 4; ++r)
                gxp[wave][m * 16 + qr + r][lrow] = acc[m][r];
        __syncthreads();
        if (tid >= 256) {
            float4 vb = *(const float4*)&Vbias[n0 + (lhc << 2)];
            float4 res = vb;
            #pragma unroll
            for (int w = 0; w < 8; ++w) {
                float4 s = *(const float4*)&gxp[w][ob][lhc << 2];
                res.x += s.x; res.y += s.y; res.z += s.z; res.w += s.w;
            }
            *(float4*)&out[131072 + (size_t)ob * 1024 + n0 + (lhc << 2)] = res;
        }
    }
}

extern "C" void kernel_launch(void* const* d_in, const int* in_sizes, int n_in,
                              void* d_out, int out_size, void* d_ws, size_t ws_size,
                              hipStream_t stream) {
    const float* x   = (const float*)d_in[0];
    const float* Wf  = (const float*)d_in[1];
    const float* bf_ = (const float*)d_in[2];
    const float* Wi  = (const float*)d_in[3];
    const float* bi_ = (const float*)d_in[4];
    const float* Wc  = (const float*)d_in[5];
    const float* bc_ = (const float*)d_in[6];
    const float* Wo  = (const float*)d_in[7];
    const float* bo_ = (const float*)d_in[8];
    const float* Vw  = (const float*)d_in[9];
    const float* Vb  = (const float*)d_in[10];

    char* ws = (char*)d_ws;
    unsigned short* Wr     = (unsigned short*)(ws + WOFF);
    unsigned short* Vbf    = (unsigned short*)(ws + VOFF);
    float*          bias_r = (float*)(ws + BOFF);
    unsigned short* hm     = (unsigned short*)(ws + HMOFF);
    unsigned short* xbb    = (unsigned short*)(ws + XBOFF);
    float*          outp   = (float*)d_out;

    cvt_x <<<8192, 256, 0, stream>>>(x, xbb);
    cvt_w <<<4096, 256, 0, stream>>>(Wf, Wi, Wo, Wc, bf_, bi_, bo_, bc_, Wr, bias_r);
    cvt_v <<<512, 256, 0, stream>>>(Vw, Vbf);
    init_h<<<32, 256, 0, stream>>>(hm);                          // buffer 0 = h_0 = 0
    init_sent<<<8192, 256, 0, stream>>>(hm + 65536);             // buffers 1..256 = sentinel

    void* args[] = {&xbb, &Wr, &bias_r, &hm, &Vbf, (void*)&Vb, &outp};
    hipLaunchCooperativeKernel((const void*)lstm_core, dim3(256), dim3(512), args, 0, stream);
}